// Round 7
// baseline (416.558 us; speedup 1.0000x reference)
//
#include <hip/hip_runtime.h>
#include <hip/hip_bf16.h>
#include <stdint.h>

#define SEQ 2048
#define BAT 32
#define EDIM 1024
#define MROWS (SEQ*BAT)   // 65536

typedef __bf16 bf16x8 __attribute__((ext_vector_type(8)));
typedef float f32x4 __attribute__((ext_vector_type(4)));
typedef unsigned short u16x8 __attribute__((ext_vector_type(8)));

typedef __attribute__((address_space(3))) unsigned int lds_uint;
typedef const __attribute__((address_space(1))) unsigned int glb_uint;

__device__ __forceinline__ void async16(void* lds, const void* g) {
  __builtin_amdgcn_global_load_lds((glb_uint*)g, (lds_uint*)lds, 16, 0, 0);
}

__device__ __forceinline__ unsigned short f2bf(float f) {
  unsigned u = __builtin_bit_cast(unsigned, f);
  u = (u + 0x7FFFu + ((u >> 16) & 1u)) >> 16;
  return (unsigned short)u;
}
__device__ __forceinline__ float bf2f(unsigned short h) {
  return __builtin_bit_cast(float, (unsigned)h << 16);
}

// hardware cvt (RNE): compiler emits v_cvt_pk_bf16_f32 pairs
__device__ __forceinline__ u16x8 cvt8(float4 a, float4 b) {
  bf16x8 r;
  r[0] = (__bf16)a.x; r[1] = (__bf16)a.y; r[2] = (__bf16)a.z; r[3] = (__bf16)a.w;
  r[4] = (__bf16)b.x; r[5] = (__bf16)b.y; r[6] = (__bf16)b.z; r[7] = (__bf16)b.w;
  return __builtin_bit_cast(u16x8, r);
}

// fast tanh: (e^{2x}-1)/(e^{2x}+1), clamped; ~7 VALU ops vs ~25 for ocml tanhf
__device__ __forceinline__ float fast_tanh(float x) {
  float xc = fminf(fmaxf(x, -9.f), 9.f);
  float e = __expf(2.f * xc);
  return (e - 1.f) * __builtin_amdgcn_rcpf(e + 1.f);
}

// ---------------- Kernel A: nv = g * v / ||v|| ----------------
__global__ void k_nv(const float* __restrict__ v, const float* __restrict__ g,
                     float* __restrict__ nv) {
  __shared__ float red[256];
  int t = threadIdx.x;
  float s = 0.f;
  for (int i = t; i < EDIM; i += 256) { float x = v[i]; s += x * x; }
  red[t] = s; __syncthreads();
  for (int o = 128; o > 0; o >>= 1) {
    if (t < o) red[t] += red[t + o];
    __syncthreads();
  }
  float scale = g[0] / sqrtf(red[0]);
  for (int i = t; i < EDIM; i += 256) nv[i] = v[i] * scale;
}

// ---------------- Kernel B: pqb[b][e] = query[b]·Wq[e] + bias[e] ----------------
__global__ void k_pqb(const float* __restrict__ query, const float* __restrict__ Wq,
                      const float* __restrict__ bias, float* __restrict__ pqb) {
  __shared__ float wq[1024];
  int e = blockIdx.x;
  int t = threadIdx.x;
  reinterpret_cast<float4*>(wq)[t] =
      reinterpret_cast<const float4*>(Wq + (size_t)e * EDIM)[t];
  __syncthreads();
  int w = t >> 6, lane = t & 63;
  float be = bias[e];
  for (int bb = 0; bb < 8; ++bb) {
    int b_ = w * 8 + bb;
    const float4* q4 = reinterpret_cast<const float4*>(query + (size_t)b_ * EDIM) + lane * 4;
    const float4* w4 = reinterpret_cast<const float4*>(wq) + lane * 4;
    float s = 0.f;
#pragma unroll
    for (int j = 0; j < 4; ++j) {
      float4 a = q4[j], c = w4[j];
      s += a.x * c.x + a.y * c.y + a.z * c.z + a.w * c.w;
    }
#pragma unroll
    for (int m = 32; m > 0; m >>= 1) s += __shfl_xor(s, m);
    if (lane == 0) pqb[(size_t)b_ * EDIM + e] = s + be;
  }
}

// ---------------- Kernel C: fp32 -> bf16 convert (Wv only now) ----------------
__global__ void k_cvt(const float* __restrict__ in, unsigned short* __restrict__ out,
                      long long n8) {
  long long i = (long long)blockIdx.x * blockDim.x + threadIdx.x;
  long long stride = (long long)gridDim.x * blockDim.x;
  for (; i < n8; i += stride) {
    const float4* p = reinterpret_cast<const float4*>(in + i * 8);
    float4 a = p[0], b = p[1];
    *reinterpret_cast<u16x8*>(out + i * 8) = cvt8(a, b);
  }
}

// ---------------- Kernel D: 256x256-tile pipelined GEMM, fused fp32->bf16 A-staging ----
// 8 waves (2M x 4N), BK=64, double-buffered 128 KiB LDS, T2 XOR swizzle (proven
// conflict-free at 128B rows). A is reg-staged straight from fp32 `value`
// (loads at tile top, cvt+swizzled ds_write at tile bottom -> latency hidden
// under the 64-MFMA phase). ni_blk==0 blocks also stream the bf16 panel to Vb
// for k_ctx. B stays on the async16 inverse-swizzled-source path.
__global__ __launch_bounds__(512, 1) void k_gemm(
    const float* __restrict__ value,        // [MROWS][1024] fp32
    const unsigned short* __restrict__ Bm,  // [1024][1024] bf16 bits
    const float* __restrict__ pqb,          // [32][1024]
    const float* __restrict__ nv,           // [1024]
    unsigned short* __restrict__ Vb,        // [MROWS][1024] bf16 out
    float* __restrict__ part)               // [4][MROWS]
{
  // slot s: A at s*65536, B at s*65536+32768; partLds at 131072
  __shared__ char smem[2 * 65536 + 4 * 256 * 4];

  const int tid = threadIdx.x;
  const int lane = tid & 63;
  const int wid = tid >> 6;
  const int wm = wid >> 2;                  // 0..1
  const int wn = wid & 3;                   // 0..3

  // XCD-chunked mapping: 4 ni-siblings of one A-panel adjacent on one XCD.
  const int bid = blockIdx.x;               // 0..1023
  const int xcd = bid & 7;
  const int j = bid >> 3;                   // 0..127
  const int mi_blk = xcd * 32 + (j >> 2);
  const int ni_blk = j & 3;
  const size_t m0 = (size_t)mi_blk * 256;
  const int n0 = ni_blk * 256;
  const bool doVb = (ni_blk == 0);

  float* partLds = (float*)(smem + 131072);

  f32x4 acc[8][4];
#pragma unroll
  for (int i = 0; i < 8; ++i)
#pragma unroll
    for (int jj = 0; jj < 4; ++jj) acc[i][jj] = f32x4{0.f, 0.f, 0.f, 0.f};

  // ---- A staging (fp32 -> reg -> cvt -> swizzled ds_write) ----
  // 4 chunks/thread: chunk i -> row = i*64 + (tid>>3), logical pos = tid&7.
  // stored pos = (tid&7) ^ (row&7) = csrc (row&7 == (tid>>3)&7 for all i).
  const int csrc = (tid & 7) ^ ((tid >> 3) & 7);
  const int rowt = tid >> 3;                // 0..63
  const float* gvA[4];
  unsigned short* vbo[4];
#pragma unroll
  for (int i = 0; i < 4; ++i) {
    size_t row = m0 + (size_t)(i * 64 + rowt);
    gvA[i] = value + row * 1024 + (tid & 7) * 8;
    vbo[i] = Vb + row * 1024 + (tid & 7) * 8;
  }
  const int dstA0 = rowt * 128 + csrc * 16;  // + i*8192 per chunk
  float4 ar[8];

  auto loadA = [&]() {
#pragma unroll
    for (int i = 0; i < 4; ++i) {
      ar[2 * i]     = *reinterpret_cast<const float4*>(gvA[i]);
      ar[2 * i + 1] = *reinterpret_cast<const float4*>(gvA[i] + 4);
    }
  };
  auto writeA = [&](char* nb) {
#pragma unroll
    for (int i = 0; i < 4; ++i) {
      u16x8 c = cvt8(ar[2 * i], ar[2 * i + 1]);
      *reinterpret_cast<u16x8*>(nb + i * 8192 + dstA0) = c;
      if (doVb) *reinterpret_cast<u16x8*>(vbo[i]) = c;
      gvA[i] += 64;
      vbo[i] += 64;
    }
  };

  // ---- B staging (async16, inverse-swizzled source, proven) ----
  const unsigned short* gB[4];
#pragma unroll
  for (int i = 0; i < 4; ++i) {
    int row = i * 64 + rowt;
    gB[i] = Bm + (size_t)(n0 + row) * 1024 + csrc * 8;
  }
  const int ldsOffB = 32768 + tid * 16;
  auto stageB = [&](char* sl) {
#pragma unroll
    for (int i = 0; i < 4; ++i) {
      async16(sl + ldsOffB + i * 8192, gB[i]);
      gB[i] += 64;
    }
  };

  // ---- LDS read addressing (R4, conflict-free) ----
  const int rA = lane & 15;
  const int cs0 = (lane >> 4) ^ (lane & 7);
  const int cs1 = cs0 ^ 4;

  char* buf0 = smem;
  char* buf1 = smem + 65536;

  // prologue: tile 0 into buf0
  loadA();
  stageB(buf0);
  writeA(buf0);
  __syncthreads();

  auto body = [&](char* cb, char* nb, bool pf) {
    if (pf) loadA();              // fp32 loads for tile t+1 (hidden under MFMA)
#pragma unroll
    for (int kk = 0; kk < 2; ++kk) {
      const int cs = kk ? cs1 : cs0;
      bf16x8 af[8], bf[4];
#pragma unroll
      for (int mi = 0; mi < 8; ++mi)
        af[mi] = *reinterpret_cast<const bf16x8*>(
            cb + (wm * 128 + mi * 16 + rA) * 128 + cs * 16);
#pragma unroll
      for (int nj = 0; nj < 2; ++nj)
        bf[nj] = *reinterpret_cast<const bf16x8*>(
            cb + 32768 + (wn * 64 + nj * 16 + rA) * 128 + cs * 16);

      __builtin_amdgcn_s_setprio(1);
#pragma unroll
      for (int mi = 0; mi < 8; ++mi)
#pragma unroll
        for (int nj = 0; nj < 2; ++nj)
          acc[mi][nj] = __builtin_amdgcn_mfma_f32_16x16x32_bf16(af[mi], bf[nj], acc[mi][nj], 0, 0, 0);
      __builtin_amdgcn_s_setprio(0);

      if (kk == 0 && pf) stageB(nb);

#pragma unroll
      for (int nj = 2; nj < 4; ++nj)
        bf[nj] = *reinterpret_cast<const bf16x8*>(
            cb + 32768 + (wn * 64 + nj * 16 + rA) * 128 + cs * 16);

      __builtin_amdgcn_s_setprio(1);
#pragma unroll
      for (int mi = 0; mi < 8; ++mi)
#pragma unroll
        for (int nj = 2; nj < 4; ++nj)
          acc[mi][nj] = __builtin_amdgcn_mfma_f32_16x16x32_bf16(af[mi], bf[nj], acc[mi][nj], 0, 0, 0);
      __builtin_amdgcn_s_setprio(0);
    }
    if (pf) writeA(nb);           // cvt + swizzled ds_write + Vb stream-out
    __syncthreads();
  };

#pragma unroll 1
  for (int tt = 0; tt < 8; ++tt) {
    body(buf0, buf1, true);
    body(buf1, buf0, tt < 7);
  }

  // Epilogue: C row = wm*128+mi*16+(lane>>4)*4+r, col = n0+wn*64+nj*16+(lane&15)
  const int cgrp = lane >> 4;
  const int ccol = lane & 15;
  float nve[4];
#pragma unroll
  for (int nj = 0; nj < 4; ++nj) nve[nj] = nv[n0 + wn * 64 + nj * 16 + ccol];

#pragma unroll
  for (int mi = 0; mi < 8; ++mi) {
#pragma unroll
    for (int r = 0; r < 4; ++r) {
      int rloc = wm * 128 + mi * 16 + cgrp * 4 + r;
      int b_ = rloc & 31;   // m0 is a multiple of 256
      const float* pq = pqb + (size_t)b_ * EDIM + n0 + wn * 64 + ccol;
      float s = 0.f;
#pragma unroll
      for (int nj = 0; nj < 4; ++nj)
        s += nve[nj] * fast_tanh(acc[mi][nj][r] + pq[nj * 16]);
      s += __shfl_xor(s, 1);
      s += __shfl_xor(s, 2);
      s += __shfl_xor(s, 4);
      s += __shfl_xor(s, 8);
      if (ccol == 0) partLds[wn * 256 + rloc] = s;
    }
  }
  __syncthreads();
  if (tid < 256)
    part[(size_t)ni_blk * MROWS + m0 + tid] =
        partLds[tid] + partLds[256 + tid] + partLds[512 + tid] + partLds[768 + tid];
}

// ---------------- Kernel E: reduce 4 chunks + mask + softmax over s ----------------
__global__ void k_softmax(const float* __restrict__ part,          // [4][MROWS]
                          const unsigned char* __restrict__ mask,  // [S][B]
                          float* __restrict__ scores,              // [MROWS]
                          float* __restrict__ out_attn)            // d_out + 32768
{
  int b_ = blockIdx.x;
  int t = threadIdx.x;
  __shared__ float red[256];
  float sc[8];
  float mx = -1e30f;
#pragma unroll
  for (int i = 0; i < 8; ++i) {
    int s_ = t + i * 256;
    size_t r = (size_t)s_ * BAT + b_;
    float v = 0.f;
#pragma unroll
    for (int c = 0; c < 4; ++c) v += part[(size_t)c * MROWS + r];
    if (mask[r]) v = -1e30f;
    sc[i] = v;
    mx = fmaxf(mx, v);
  }
  red[t] = mx; __syncthreads();
  for (int o = 128; o > 0; o >>= 1) {
    if (t < o) red[t] = fmaxf(red[t], red[t + o]);
    __syncthreads();
  }
  mx = red[0];
  __syncthreads();
  float sum = 0.f;
#pragma unroll
  for (int i = 0; i < 8; ++i) { sc[i] = expf(sc[i] - mx); sum += sc[i]; }
  red[t] = sum; __syncthreads();
  for (int o = 128; o > 0; o >>= 1) {
    if (t < o) red[t] += red[t + o];
    __syncthreads();
  }
  float inv = 1.f / red[0];
#pragma unroll
  for (int i = 0; i < 8; ++i) {
    int s_ = t + i * 256;
    size_t r = (size_t)s_ * BAT + b_;
    float w = sc[i] * inv;
    scores[r] = w;
    out_attn[r] = w;
    out_attn[MROWS + r] = w;
  }
}

// ---------------- Kernel F: context partials over s-chunks ----------------
__global__ void k_ctx(const unsigned short* __restrict__ Vb,  // [MROWS][1024] bf16
                      const float* __restrict__ scores,       // [MROWS]
                      float* __restrict__ pctx)               // [16][BAT][1024]
{
  int b_ = blockIdx.x;   // 0..31
  int sch = blockIdx.y;  // 0..7
  int t = threadIdx.x;
  int d8 = t & 127;
  int sr = t >> 7;
  float acc[8];
#pragma unroll
  for (int j = 0; j < 8; ++j) acc[j] = 0.f;
  int s0 = sch * 256;
  for (int i = 0; i < 128; ++i) {
    int s_ = s0 + i * 2 + sr;
    size_t r = (size_t)s_ * BAT + b_;
    float w = scores[r];
    u16x8 v = *reinterpret_cast<const u16x8*>(Vb + r * 1024 + d8 * 8);
#pragma unroll
    for (int j = 0; j < 8; ++j) acc[j] += w * bf2f(v[j]);
  }
  float* dst = pctx + ((size_t)(sch * 2 + sr) * BAT + b_) * 1024 + d8 * 8;
#pragma unroll
  for (int j = 0; j < 8; ++j) dst[j] = acc[j];
}

// ---------------- Kernel G: final context reduce ----------------
__global__ void k_ctx_reduce(const float* __restrict__ pctx, float* __restrict__ out) {
  int i = blockIdx.x * 256 + threadIdx.x;  // 0..32767
  float s = 0.f;
#pragma unroll
  for (int c = 0; c < 16; ++c) s += pctx[(size_t)c * 32768 + i];
  out[i] = s;
}

extern "C" void kernel_launch(void* const* d_in, const int* in_sizes, int n_in,
                              void* d_out, int out_size, void* d_ws, size_t ws_size,
                              hipStream_t stream) {
  const float* query = (const float*)d_in[0];
  const float* value = (const float*)d_in[1];
  const float* Wq    = (const float*)d_in[2];
  const float* Wv    = (const float*)d_in[3];
  const float* v     = (const float*)d_in[4];
  const float* bias  = (const float*)d_in[5];
  const float* g     = (const float*)d_in[6];
  const unsigned char* mask = (const unsigned char*)d_in[7];
  float* out = (float*)d_out;

  char* ws = (char*)d_ws;
  unsigned short* Vb  = (unsigned short*)ws;                        // 128 MB
  unsigned short* Wvb = (unsigned short*)(ws + (size_t)134217728);  // 2 MB
  float* pqb    = (float*)(ws + (size_t)134217728 + 2097152);       // 128 KB
  float* nv     = pqb + 32 * 1024;                                  // 4 KB
  float* part   = nv + 1024;                                        // 4*65536*4 = 1 MB
  float* scores = part + 4 * MROWS;                                 // 256 KB
  float* pctx   = scores + MROWS;                                   // 2 MB

  k_nv<<<1, 256, 0, stream>>>(v, g, nv);
  k_pqb<<<1024, 256, 0, stream>>>(query, Wq, bias, pqb);
  k_cvt<<<512, 256, 0, stream>>>(Wv, Wvb, (long long)(1024LL * 1024 / 8));
  k_gemm<<<1024, 512, 0, stream>>>(value, Wvb, pqb, nv, Vb, part);
  k_softmax<<<32, 256, 0, stream>>>(part, mask, scores, out + 32768);
  dim3 gf(32, 8);
  k_ctx<<<gf, 256, 0, stream>>>(Vb, scores, pctx);
  k_ctx_reduce<<<128, 256, 0, stream>>>(pctx, out);
}

// Round 8
// 379.463 us; speedup vs baseline: 1.0978x; 1.0978x over previous
//
#include <hip/hip_runtime.h>
#include <hip/hip_bf16.h>
#include <stdint.h>

#define SEQ 2048
#define BAT 32
#define EDIM 1024
#define MROWS (SEQ*BAT)   // 65536

typedef __bf16 bf16x8 __attribute__((ext_vector_type(8)));
typedef float f32x4 __attribute__((ext_vector_type(4)));
typedef unsigned short u16x8 __attribute__((ext_vector_type(8)));

typedef __attribute__((address_space(3))) unsigned int lds_uint;
typedef const __attribute__((address_space(1))) unsigned int glb_uint;

__device__ __forceinline__ void async16(void* lds, const void* g) {
  __builtin_amdgcn_global_load_lds((glb_uint*)g, (lds_uint*)lds, 16, 0, 0);
}

__device__ __forceinline__ float bf2f(unsigned short h) {
  return __builtin_bit_cast(float, (unsigned)h << 16);
}

// hardware cvt (RNE): compiler emits v_cvt_pk_bf16_f32 pairs
__device__ __forceinline__ u16x8 cvt8(float4 a, float4 b) {
  bf16x8 r;
  r[0] = (__bf16)a.x; r[1] = (__bf16)a.y; r[2] = (__bf16)a.z; r[3] = (__bf16)a.w;
  r[4] = (__bf16)b.x; r[5] = (__bf16)b.y; r[6] = (__bf16)b.z; r[7] = (__bf16)b.w;
  return __builtin_bit_cast(u16x8, r);
}

// fast tanh: (e^{2x}-1)/(e^{2x}+1), clamped; ~7 VALU ops vs ~25 for ocml tanhf
__device__ __forceinline__ float fast_tanh(float x) {
  float xc = fminf(fmaxf(x, -9.f), 9.f);
  float e = __expf(2.f * xc);
  return (e - 1.f) * __builtin_amdgcn_rcpf(e + 1.f);
}

// ---------------- Kernel A: nv = g * v / ||v|| ----------------
__global__ void k_nv(const float* __restrict__ v, const float* __restrict__ g,
                     float* __restrict__ nv) {
  __shared__ float red[256];
  int t = threadIdx.x;
  float s = 0.f;
  for (int i = t; i < EDIM; i += 256) { float x = v[i]; s += x * x; }
  red[t] = s; __syncthreads();
  for (int o = 128; o > 0; o >>= 1) {
    if (t < o) red[t] += red[t + o];
    __syncthreads();
  }
  float scale = g[0] / sqrtf(red[0]);
  for (int i = t; i < EDIM; i += 256) nv[i] = v[i] * scale;
}

// ---------------- Kernel B: pqb[b][e] = query[b]·Wq[e] + bias[e] ----------------
__global__ void k_pqb(const float* __restrict__ query, const float* __restrict__ Wq,
                      const float* __restrict__ bias, float* __restrict__ pqb) {
  __shared__ float wq[1024];
  int e = blockIdx.x;
  int t = threadIdx.x;
  reinterpret_cast<float4*>(wq)[t] =
      reinterpret_cast<const float4*>(Wq + (size_t)e * EDIM)[t];
  __syncthreads();
  int w = t >> 6, lane = t & 63;
  float be = bias[e];
  for (int bb = 0; bb < 8; ++bb) {
    int b_ = w * 8 + bb;
    const float4* q4 = reinterpret_cast<const float4*>(query + (size_t)b_ * EDIM) + lane * 4;
    const float4* w4 = reinterpret_cast<const float4*>(wq) + lane * 4;
    float s = 0.f;
#pragma unroll
    for (int j = 0; j < 4; ++j) {
      float4 a = q4[j], c = w4[j];
      s += a.x * c.x + a.y * c.y + a.z * c.z + a.w * c.w;
    }
#pragma unroll
    for (int m = 32; m > 0; m >>= 1) s += __shfl_xor(s, m);
    if (lane == 0) pqb[(size_t)b_ * EDIM + e] = s + be;
  }
}

// ---------------- Kernel C: fp32 -> bf16 convert (Wv only) ----------------
__global__ void k_cvt(const float* __restrict__ in, unsigned short* __restrict__ out,
                      long long n8) {
  long long i = (long long)blockIdx.x * blockDim.x + threadIdx.x;
  long long stride = (long long)gridDim.x * blockDim.x;
  for (; i < n8; i += stride) {
    const float4* p = reinterpret_cast<const float4*>(in + i * 8);
    *reinterpret_cast<u16x8*>(out + i * 8) = cvt8(p[0], p[1]);
  }
}

// ---------------- Kernel D: 256x256-tile pipelined GEMM, in-kernel fp32->bf16 A ----
// R4's proven 2-phase schedule (conflicts=0). A is reg-staged from fp32 `value`:
// 8 global_load_dwordx4 at tile top (complete under the 64-MFMA phase), then
// cvt + swizzled ds_write_b128 at tile bottom. NO global stores -> the barrier's
// vmcnt(0) only drains loads that are a full MFMA-phase old. B via async16 with
// inverse-swizzled source. LDS identity: LDS[r][q] = G[r][q^(r&7)].
__global__ __launch_bounds__(512, 1) void k_gemm(
    const float* __restrict__ value,        // [MROWS][1024] fp32
    const unsigned short* __restrict__ Bm,  // [1024][1024] bf16 bits
    const float* __restrict__ pqb,          // [32][1024]
    const float* __restrict__ nv,           // [1024]
    float* __restrict__ part)               // [4][MROWS]
{
  // slot s: A at s*65536, B at s*65536+32768; partLds at 131072
  __shared__ char smem[2 * 65536 + 4 * 256 * 4];

  const int tid = threadIdx.x;
  const int lane = tid & 63;
  const int wid = tid >> 6;
  const int wm = wid >> 2;                  // 0..1
  const int wn = wid & 3;                   // 0..3

  // XCD-chunked mapping: 4 ni-siblings of one A-panel adjacent on one XCD.
  const int bid = blockIdx.x;               // 0..1023
  const int xcd = bid & 7;
  const int j = bid >> 3;                   // 0..127
  const int mi_blk = xcd * 32 + (j >> 2);
  const int ni_blk = j & 3;
  const size_t m0 = (size_t)mi_blk * 256;
  const int n0 = ni_blk * 256;

  float* partLds = (float*)(smem + 131072);

  f32x4 acc[8][4];
#pragma unroll
  for (int i = 0; i < 8; ++i)
#pragma unroll
    for (int jj = 0; jj < 4; ++jj) acc[i][jj] = f32x4{0.f, 0.f, 0.f, 0.f};

  // ---- A staging (fp32 -> reg -> cvt -> swizzled ds_write) ----
  // chunk i: row = i*64 + (tid>>3), logical source pos p = tid&7;
  // dst pos = p ^ (row&7) = csrc  (row&7 == (tid>>3)&7 for all i)
  const int csrc = (tid & 7) ^ ((tid >> 3) & 7);
  const int rowt = tid >> 3;                // 0..63
  const float* gvA[4];
#pragma unroll
  for (int i = 0; i < 4; ++i)
    gvA[i] = value + (m0 + (size_t)(i * 64 + rowt)) * 1024 + (tid & 7) * 8;
  const int dstA0 = rowt * 128 + csrc * 16;  // + i*8192 per chunk
  float4 ar[8];

  auto loadA = [&]() {
#pragma unroll
    for (int i = 0; i < 4; ++i) {
      ar[2 * i]     = *reinterpret_cast<const float4*>(gvA[i]);
      ar[2 * i + 1] = *reinterpret_cast<const float4*>(gvA[i] + 4);
      gvA[i] += 64;
    }
  };
  auto writeA = [&](char* nb) {
#pragma unroll
    for (int i = 0; i < 4; ++i)
      *reinterpret_cast<u16x8*>(nb + i * 8192 + dstA0) = cvt8(ar[2 * i], ar[2 * i + 1]);
  };

  // ---- B staging (async16, inverse-swizzled source, proven) ----
  const unsigned short* gB[4];
#pragma unroll
  for (int i = 0; i < 4; ++i)
    gB[i] = Bm + (size_t)(n0 + i * 64 + rowt) * 1024 + csrc * 8;
  const int ldsOffB = 32768 + tid * 16;
  auto stageB = [&](char* sl) {
#pragma unroll
    for (int i = 0; i < 4; ++i) {
      async16(sl + ldsOffB + i * 8192, gB[i]);
      gB[i] += 64;
    }
  };

  // ---- LDS read addressing (R4, conflict-free) ----
  const int rA = lane & 15;
  const int cs0 = (lane >> 4) ^ (lane & 7);
  const int cs1 = cs0 ^ 4;

  char* buf0 = smem;
  char* buf1 = smem + 65536;

  // prologue: tile 0 into buf0
  loadA();
  stageB(buf0);
  writeA(buf0);
  __syncthreads();

  auto body = [&](char* cb, char* nb, bool pf) {
    if (pf) loadA();              // fp32 loads for tile t+1 (hidden under MFMA)
#pragma unroll
    for (int kk = 0; kk < 2; ++kk) {
      const int cs = kk ? cs1 : cs0;
      bf16x8 af[8], bf[4];
#pragma unroll
      for (int mi = 0; mi < 8; ++mi)
        af[mi] = *reinterpret_cast<const bf16x8*>(
            cb + (wm * 128 + mi * 16 + rA) * 128 + cs * 16);
#pragma unroll
      for (int nj = 0; nj < 2; ++nj)
        bf[nj] = *reinterpret_cast<const bf16x8*>(
            cb + 32768 + (wn * 64 + nj * 16 + rA) * 128 + cs * 16);

      __builtin_amdgcn_s_setprio(1);
#pragma unroll
      for (int mi = 0; mi < 8; ++mi)
#pragma unroll
        for (int nj = 0; nj < 2; ++nj)
          acc[mi][nj] = __builtin_amdgcn_mfma_f32_16x16x32_bf16(af[mi], bf[nj], acc[mi][nj], 0, 0, 0);
      __builtin_amdgcn_s_setprio(0);

      if (kk == 0 && pf) stageB(nb);

#pragma unroll
      for (int nj = 2; nj < 4; ++nj)
        bf[nj] = *reinterpret_cast<const bf16x8*>(
            cb + 32768 + (wn * 64 + nj * 16 + rA) * 128 + cs * 16);

      __builtin_amdgcn_s_setprio(1);
#pragma unroll
      for (int mi = 0; mi < 8; ++mi)
#pragma unroll
        for (int nj = 2; nj < 4; ++nj)
          acc[mi][nj] = __builtin_amdgcn_mfma_f32_16x16x32_bf16(af[mi], bf[nj], acc[mi][nj], 0, 0, 0);
      __builtin_amdgcn_s_setprio(0);
    }
    if (pf) writeA(nb);           // cvt + swizzled ds_write (LDS only, no stores)
    __syncthreads();
  };

#pragma unroll 1
  for (int tt = 0; tt < 8; ++tt) {
    body(buf0, buf1, true);
    body(buf1, buf0, tt < 7);
  }

  // Epilogue: C row = wm*128+mi*16+(lane>>4)*4+r, col = n0+wn*64+nj*16+(lane&15)
  const int cgrp = lane >> 4;
  const int ccol = lane & 15;
  float nve[4];
#pragma unroll
  for (int nj = 0; nj < 4; ++nj) nve[nj] = nv[n0 + wn * 64 + nj * 16 + ccol];

#pragma unroll
  for (int mi = 0; mi < 8; ++mi) {
#pragma unroll
    for (int r = 0; r < 4; ++r) {
      int rloc = wm * 128 + mi * 16 + cgrp * 4 + r;
      int b_ = rloc & 31;   // m0 is a multiple of 256
      const float* pq = pqb + (size_t)b_ * EDIM + n0 + wn * 64 + ccol;
      float s = 0.f;
#pragma unroll
      for (int nj = 0; nj < 4; ++nj)
        s += nve[nj] * fast_tanh(acc[mi][nj][r] + pq[nj * 16]);
      s += __shfl_xor(s, 1);
      s += __shfl_xor(s, 2);
      s += __shfl_xor(s, 4);
      s += __shfl_xor(s, 8);
      if (ccol == 0) partLds[wn * 256 + rloc] = s;
    }
  }
  __syncthreads();
  if (tid < 256)
    part[(size_t)ni_blk * MROWS + m0 + tid] =
        partLds[tid] + partLds[256 + tid] + partLds[512 + tid] + partLds[768 + tid];
}

// ---------------- Kernel E: reduce 4 chunks + mask + softmax over s ----------------
__global__ void k_softmax(const float* __restrict__ part,          // [4][MROWS]
                          const unsigned char* __restrict__ mask,  // [S][B]
                          float* __restrict__ scores,              // [MROWS]
                          float* __restrict__ out_attn)            // d_out + 32768
{
  int b_ = blockIdx.x;
  int t = threadIdx.x;
  __shared__ float red[256];
  float sc[8];
  float mx = -1e30f;
#pragma unroll
  for (int i = 0; i < 8; ++i) {
    int s_ = t + i * 256;
    size_t r = (size_t)s_ * BAT + b_;
    float v = 0.f;
#pragma unroll
    for (int c = 0; c < 4; ++c) v += part[(size_t)c * MROWS + r];
    if (mask[r]) v = -1e30f;
    sc[i] = v;
    mx = fmaxf(mx, v);
  }
  red[t] = mx; __syncthreads();
  for (int o = 128; o > 0; o >>= 1) {
    if (t < o) red[t] = fmaxf(red[t], red[t + o]);
    __syncthreads();
  }
  mx = red[0];
  __syncthreads();
  float sum = 0.f;
#pragma unroll
  for (int i = 0; i < 8; ++i) { sc[i] = expf(sc[i] - mx); sum += sc[i]; }
  red[t] = sum; __syncthreads();
  for (int o = 128; o > 0; o >>= 1) {
    if (t < o) red[t] += red[t + o];
    __syncthreads();
  }
  float inv = 1.f / red[0];
#pragma unroll
  for (int i = 0; i < 8; ++i) {
    int s_ = t + i * 256;
    size_t r = (size_t)s_ * BAT + b_;
    float w = sc[i] * inv;
    scores[r] = w;
    out_attn[r] = w;
    out_attn[MROWS + r] = w;
  }
}

// ---------------- Kernel F: context partials over s-chunks (fp32 value) ----------------
__global__ void k_ctx(const float* __restrict__ value,   // [MROWS][1024] fp32
                      const float* __restrict__ scores,  // [MROWS]
                      float* __restrict__ pctx)          // [16][BAT][1024]
{
  int b_ = blockIdx.x;   // 0..31
  int sch = blockIdx.y;  // 0..7
  int t = threadIdx.x;
  int d8 = t & 127;
  int sr = t >> 7;
  float acc[8];
#pragma unroll
  for (int j = 0; j < 8; ++j) acc[j] = 0.f;
  int s0 = sch * 256;
  for (int i = 0; i < 128; ++i) {
    int s_ = s0 + i * 2 + sr;
    size_t r = (size_t)s_ * BAT + b_;
    float w = scores[r];
    const float4* p = reinterpret_cast<const float4*>(value + r * 1024 + d8 * 8);
    float4 a = p[0], b = p[1];
    acc[0] += w * a.x; acc[1] += w * a.y; acc[2] += w * a.z; acc[3] += w * a.w;
    acc[4] += w * b.x; acc[5] += w * b.y; acc[6] += w * b.z; acc[7] += w * b.w;
  }
  float* dst = pctx + ((size_t)(sch * 2 + sr) * BAT + b_) * 1024 + d8 * 8;
#pragma unroll
  for (int j = 0; j < 8; ++j) dst[j] = acc[j];
}

// ---------------- Kernel G: final context reduce ----------------
__global__ void k_ctx_reduce(const float* __restrict__ pctx, float* __restrict__ out) {
  int i = blockIdx.x * 256 + threadIdx.x;  // 0..32767
  float s = 0.f;
#pragma unroll
  for (int c = 0; c < 16; ++c) s += pctx[(size_t)c * 32768 + i];
  out[i] = s;
}

extern "C" void kernel_launch(void* const* d_in, const int* in_sizes, int n_in,
                              void* d_out, int out_size, void* d_ws, size_t ws_size,
                              hipStream_t stream) {
  const float* query = (const float*)d_in[0];
  const float* value = (const float*)d_in[1];
  const float* Wq    = (const float*)d_in[2];
  const float* Wv    = (const float*)d_in[3];
  const float* v     = (const float*)d_in[4];
  const float* bias  = (const float*)d_in[5];
  const float* g     = (const float*)d_in[6];
  const unsigned char* mask = (const unsigned char*)d_in[7];
  float* out = (float*)d_out;

  char* ws = (char*)d_ws;
  unsigned short* Wvb = (unsigned short*)ws;                        // 2 MB
  float* pqb    = (float*)(ws + 2097152);                           // 128 KB
  float* nv     = pqb + 32 * 1024;                                  // 4 KB
  float* part   = nv + 1024;                                        // 4*65536*4 = 1 MB
  float* scores = part + 4 * MROWS;                                 // 256 KB
  float* pctx   = scores + MROWS;                                   // 2 MB

  k_nv<<<1, 256, 0, stream>>>(v, g, nv);
  k_pqb<<<1024, 256, 0, stream>>>(query, Wq, bias, pqb);
  k_cvt<<<512, 256, 0, stream>>>(Wv, Wvb, (long long)(1024LL * 1024 / 8));
  k_gemm<<<1024, 512, 0, stream>>>(value, Wvb, pqb, nv, part);
  k_softmax<<<32, 256, 0, stream>>>(part, mask, scores, out + 32768);
  dim3 gf(32, 8);
  k_ctx<<<gf, 256, 0, stream>>>(value, scores, pctx);
  k_ctx_reduce<<<128, 256, 0, stream>>>(pctx, out);
}

// Round 9
// 250.595 us; speedup vs baseline: 1.6623x; 1.5143x over previous
//
#include <hip/hip_runtime.h>
#include <hip/hip_bf16.h>
#include <stdint.h>

#define SEQ 2048
#define BAT 32
#define EDIM 1024
#define MROWS (SEQ*BAT)   // 65536

typedef __bf16 bf16x8 __attribute__((ext_vector_type(8)));
typedef float f32x4 __attribute__((ext_vector_type(4)));
typedef unsigned short u16x8 __attribute__((ext_vector_type(8)));

typedef __attribute__((address_space(3))) unsigned int lds_uint;
typedef const __attribute__((address_space(1))) unsigned int glb_uint;

__device__ __forceinline__ void async16(void* lds, const void* g) {
  __builtin_amdgcn_global_load_lds((glb_uint*)g, (lds_uint*)lds, 16, 0, 0);
}

// hardware cvt (RNE): compiler emits v_cvt_pk_bf16_f32 pairs
__device__ __forceinline__ u16x8 cvt8(float4 a, float4 b) {
  bf16x8 r;
  r[0] = (__bf16)a.x; r[1] = (__bf16)a.y; r[2] = (__bf16)a.z; r[3] = (__bf16)a.w;
  r[4] = (__bf16)b.x; r[5] = (__bf16)b.y; r[6] = (__bf16)b.z; r[7] = (__bf16)b.w;
  return __builtin_bit_cast(u16x8, r);
}

// fast tanh: (e^{2x}-1)/(e^{2x}+1), clamped; ~7 VALU ops vs ~25 for ocml tanhf
__device__ __forceinline__ float fast_tanh(float x) {
  float xc = fminf(fmaxf(x, -9.f), 9.f);
  float e = __expf(2.f * xc);
  return (e - 1.f) * __builtin_amdgcn_rcpf(e + 1.f);
}

// ---------------- Kernel A: nv = g * v / ||v|| ----------------
__global__ void k_nv(const float* __restrict__ v, const float* __restrict__ g,
                     float* __restrict__ nv) {
  __shared__ float red[256];
  int t = threadIdx.x;
  float s = 0.f;
  for (int i = t; i < EDIM; i += 256) { float x = v[i]; s += x * x; }
  red[t] = s; __syncthreads();
  for (int o = 128; o > 0; o >>= 1) {
    if (t < o) red[t] += red[t + o];
    __syncthreads();
  }
  float scale = g[0] / sqrtf(red[0]);
  for (int i = t; i < EDIM; i += 256) nv[i] = v[i] * scale;
}

// ---------------- Kernel B: pqb[b][e] = query[b]·Wq[e] + bias[e] ----------------
__global__ void k_pqb(const float* __restrict__ query, const float* __restrict__ Wq,
                      const float* __restrict__ bias, float* __restrict__ pqb) {
  __shared__ float wq[1024];
  int e = blockIdx.x;
  int t = threadIdx.x;
  reinterpret_cast<float4*>(wq)[t] =
      reinterpret_cast<const float4*>(Wq + (size_t)e * EDIM)[t];
  __syncthreads();
  int w = t >> 6, lane = t & 63;
  float be = bias[e];
  for (int bb = 0; bb < 8; ++bb) {
    int b_ = w * 8 + bb;
    const float4* q4 = reinterpret_cast<const float4*>(query + (size_t)b_ * EDIM) + lane * 4;
    const float4* w4 = reinterpret_cast<const float4*>(wq) + lane * 4;
    float s = 0.f;
#pragma unroll
    for (int j = 0; j < 4; ++j) {
      float4 a = q4[j], c = w4[j];
      s += a.x * c.x + a.y * c.y + a.z * c.z + a.w * c.w;
    }
#pragma unroll
    for (int m = 32; m > 0; m >>= 1) s += __shfl_xor(s, m);
    if (lane == 0) pqb[(size_t)b_ * EDIM + e] = s + be;
  }
}

// ---------------- Kernel C: fp32 -> bf16 convert (Wv only) ----------------
__global__ void k_cvt(const float* __restrict__ in, unsigned short* __restrict__ out,
                      long long n8) {
  long long i = (long long)blockIdx.x * blockDim.x + threadIdx.x;
  long long stride = (long long)gridDim.x * blockDim.x;
  for (; i < n8; i += stride) {
    const float4* p = reinterpret_cast<const float4*>(in + i * 8);
    *reinterpret_cast<u16x8*>(out + i * 8) = cvt8(p[0], p[1]);
  }
}

// ---------------- Kernel D: 256x256-tile pipelined GEMM, in-kernel fp32->bf16 A ----
// R4's proven 2-phase schedule. A reg-staged from fp32 `value` in TWO HALVES
// of 2 chunks (16 VGPR live, shared ar[4] -> allocator reuses; no spill):
//   loadA(h0) | kk=0 clusters | writeA(h0), loadA(h1) | kk=1 clusters | writeA(h1) | bar
// No global stores in the loop -> barrier vmcnt drains only old loads.
// B via async16 with inverse-swizzled source. LDS identity: LDS[r][q]=G[r][q^(r&7)].
__global__ __launch_bounds__(512, 1) void k_gemm(
    const float* __restrict__ value,        // [MROWS][1024] fp32
    const unsigned short* __restrict__ Bm,  // [1024][1024] bf16 bits
    const float* __restrict__ pqb,          // [32][1024]
    const float* __restrict__ nv,           // [1024]
    float* __restrict__ part)               // [4][MROWS]
{
  // slot s: A at s*65536, B at s*65536+32768; partLds at 131072
  __shared__ char smem[2 * 65536 + 4 * 256 * 4];

  const int tid = threadIdx.x;
  const int lane = tid & 63;
  const int wid = tid >> 6;
  const int wm = wid >> 2;                  // 0..1
  const int wn = wid & 3;                   // 0..3

  // XCD-chunked mapping: 4 ni-siblings of one A-panel adjacent on one XCD.
  const int bid = blockIdx.x;               // 0..1023
  const int xcd = bid & 7;
  const int j = bid >> 3;                   // 0..127
  const int mi_blk = xcd * 32 + (j >> 2);
  const int ni_blk = j & 3;
  const size_t m0 = (size_t)mi_blk * 256;
  const int n0 = ni_blk * 256;

  float* partLds = (float*)(smem + 131072);

  f32x4 acc[8][4];
#pragma unroll
  for (int i = 0; i < 8; ++i)
#pragma unroll
    for (int jj = 0; jj < 4; ++jj) acc[i][jj] = f32x4{0.f, 0.f, 0.f, 0.f};

  // ---- A staging (fp32 -> reg -> cvt -> swizzled ds_write), 2 halves ----
  // chunk c: row = c*64 + (tid>>3), logical source pos p = tid&7;
  // dst pos = p ^ (row&7) = csrc  (row&7 == (tid>>3)&7 for all c)
  const int csrc = (tid & 7) ^ ((tid >> 3) & 7);
  const int rowt = tid >> 3;                // 0..63
  const float* gvA[4];
#pragma unroll
  for (int i = 0; i < 4; ++i)
    gvA[i] = value + (m0 + (size_t)(i * 64 + rowt)) * 1024 + (tid & 7) * 8;
  const int dstA0 = rowt * 128 + csrc * 16;  // + c*8192 per chunk

  float4 ar[4];   // ONE shared 16-VGPR staging block; WAR dep stops overlap

  auto loadAh = [&](int h) {
#pragma unroll
    for (int i = 0; i < 2; ++i) {
      int c = 2 * h + i;
      ar[2 * i]     = *reinterpret_cast<const float4*>(gvA[c]);
      ar[2 * i + 1] = *reinterpret_cast<const float4*>(gvA[c] + 4);
      gvA[c] += 64;
    }
  };
  auto writeAh = [&](char* nb, int h) {
#pragma unroll
    for (int i = 0; i < 2; ++i) {
      int c = 2 * h + i;
      *reinterpret_cast<u16x8*>(nb + c * 8192 + dstA0) = cvt8(ar[2 * i], ar[2 * i + 1]);
    }
  };

  // ---- B staging (async16, inverse-swizzled source, proven) ----
  const unsigned short* gB[4];
#pragma unroll
  for (int i = 0; i < 4; ++i)
    gB[i] = Bm + (size_t)(n0 + i * 64 + rowt) * 1024 + csrc * 8;
  const int ldsOffB = 32768 + tid * 16;
  auto stageB = [&](char* sl) {
#pragma unroll
    for (int i = 0; i < 4; ++i) {
      async16(sl + ldsOffB + i * 8192, gB[i]);
      gB[i] += 64;
    }
  };

  // ---- LDS read addressing (R4, conflict-free) ----
  const int rA = lane & 15;
  const int cs0 = (lane >> 4) ^ (lane & 7);
  const int cs1 = cs0 ^ 4;

  char* buf0 = smem;
  char* buf1 = smem + 65536;

  // prologue: tile 0 into buf0 (stalls on loads once; not in steady state)
  loadAh(0);
  stageB(buf0);
  writeAh(buf0, 0);
  loadAh(1);
  writeAh(buf0, 1);
  __syncthreads();

  auto body = [&](char* cb, char* nb, bool pf) {
    if (pf) loadAh(0);            // fp32 half 0 for tile t+1

    // ---- kk = 0 ----
    {
      bf16x8 af[8], bf[4];
#pragma unroll
      for (int mi = 0; mi < 8; ++mi)
        af[mi] = *reinterpret_cast<const bf16x8*>(
            cb + (wm * 128 + mi * 16 + rA) * 128 + cs0 * 16);
#pragma unroll
      for (int nj = 0; nj < 2; ++nj)
        bf[nj] = *reinterpret_cast<const bf16x8*>(
            cb + 32768 + (wn * 64 + nj * 16 + rA) * 128 + cs0 * 16);

      __builtin_amdgcn_s_setprio(1);
#pragma unroll
      for (int mi = 0; mi < 8; ++mi)
#pragma unroll
        for (int nj = 0; nj < 2; ++nj)
          acc[mi][nj] = __builtin_amdgcn_mfma_f32_16x16x32_bf16(af[mi], bf[nj], acc[mi][nj], 0, 0, 0);
      __builtin_amdgcn_s_setprio(0);

      if (pf) stageB(nb);

#pragma unroll
      for (int nj = 2; nj < 4; ++nj)
        bf[nj] = *reinterpret_cast<const bf16x8*>(
            cb + 32768 + (wn * 64 + nj * 16 + rA) * 128 + cs0 * 16);

      __builtin_amdgcn_s_setprio(1);
#pragma unroll
      for (int mi = 0; mi < 8; ++mi)
#pragma unroll
        for (int nj = 2; nj < 4; ++nj)
          acc[mi][nj] = __builtin_amdgcn_mfma_f32_16x16x32_bf16(af[mi], bf[nj], acc[mi][nj], 0, 0, 0);
      __builtin_amdgcn_s_setprio(0);
    }

    if (pf) {
      writeAh(nb, 0);             // half 0: loads are ~2 MFMA clusters old
      loadAh(1);                  // reuses ar[] (WAR: cannot hoist above write)
    }

    // ---- kk = 1 ----
    {
      bf16x8 af[8], bf[4];
#pragma unroll
      for (int mi = 0; mi < 8; ++mi)
        af[mi] = *reinterpret_cast<const bf16x8*>(
            cb + (wm * 128 + mi * 16 + rA) * 128 + cs1 * 16);
#pragma unroll
      for (int nj = 0; nj < 2; ++nj)
        bf[nj] = *reinterpret_cast<const bf16x8*>(
            cb + 32768 + (wn * 64 + nj * 16 + rA) * 128 + cs1 * 16);

      __builtin_amdgcn_s_setprio(1);
#pragma unroll
      for (int mi = 0; mi < 8; ++mi)
#pragma unroll
        for (int nj = 0; nj < 2; ++nj)
          acc[mi][nj] = __builtin_amdgcn_mfma_f32_16x16x32_bf16(af[mi], bf[nj], acc[mi][nj], 0, 0, 0);
      __builtin_amdgcn_s_setprio(0);

#pragma unroll
      for (int nj = 2; nj < 4; ++nj)
        bf[nj] = *reinterpret_cast<const bf16x8*>(
            cb + 32768 + (wn * 64 + nj * 16 + rA) * 128 + cs1 * 16);

      __builtin_amdgcn_s_setprio(1);
#pragma unroll
      for (int mi = 0; mi < 8; ++mi)
#pragma unroll
        for (int nj = 2; nj < 4; ++nj)
          acc[mi][nj] = __builtin_amdgcn_mfma_f32_16x16x32_bf16(af[mi], bf[nj], acc[mi][nj], 0, 0, 0);
      __builtin_amdgcn_s_setprio(0);
    }

    if (pf) writeAh(nb, 1);       // half 1: loads are ~2 MFMA clusters old
    __syncthreads();
  };

#pragma unroll 1
  for (int tt = 0; tt < 8; ++tt) {
    body(buf0, buf1, true);
    body(buf1, buf0, tt < 7);
  }

  // Epilogue: C row = wm*128+mi*16+(lane>>4)*4+r, col = n0+wn*64+nj*16+(lane&15)
  const int cgrp = lane >> 4;
  const int ccol = lane & 15;
  float nve[4];
#pragma unroll
  for (int nj = 0; nj < 4; ++nj) nve[nj] = nv[n0 + wn * 64 + nj * 16 + ccol];

#pragma unroll
  for (int mi = 0; mi < 8; ++mi) {
#pragma unroll
    for (int r = 0; r < 4; ++r) {
      int rloc = wm * 128 + mi * 16 + cgrp * 4 + r;
      int b_ = rloc & 31;   // m0 is a multiple of 256
      const float* pq = pqb + (size_t)b_ * EDIM + n0 + wn * 64 + ccol;
      float s = 0.f;
#pragma unroll
      for (int nj = 0; nj < 4; ++nj)
        s += nve[nj] * fast_tanh(acc[mi][nj][r] + pq[nj * 16]);
      s += __shfl_xor(s, 1);
      s += __shfl_xor(s, 2);
      s += __shfl_xor(s, 4);
      s += __shfl_xor(s, 8);
      if (ccol == 0) partLds[wn * 256 + rloc] = s;
    }
  }
  __syncthreads();
  if (tid < 256)
    part[(size_t)ni_blk * MROWS + m0 + tid] =
        partLds[tid] + partLds[256 + tid] + partLds[512 + tid] + partLds[768 + tid];
}

// ---------------- Kernel E: reduce 4 chunks + mask + softmax over s ----------------
__global__ void k_softmax(const float* __restrict__ part,          // [4][MROWS]
                          const unsigned char* __restrict__ mask,  // [S][B]
                          float* __restrict__ scores,              // [MROWS]
                          float* __restrict__ out_attn)            // d_out + 32768
{
  int b_ = blockIdx.x;
  int t = threadIdx.x;
  __shared__ float red[256];
  float sc[8];
  float mx = -1e30f;
#pragma unroll
  for (int i = 0; i < 8; ++i) {
    int s_ = t + i * 256;
    size_t r = (size_t)s_ * BAT + b_;
    float v = 0.f;
#pragma unroll
    for (int c = 0; c < 4; ++c) v += part[(size_t)c * MROWS + r];
    if (mask[r]) v = -1e30f;
    sc[i] = v;
    mx = fmaxf(mx, v);
  }
  red[t] = mx; __syncthreads();
  for (int o = 128; o > 0; o >>= 1) {
    if (t < o) red[t] = fmaxf(red[t], red[t + o]);
    __syncthreads();
  }
  mx = red[0];
  __syncthreads();
  float sum = 0.f;
#pragma unroll
  for (int i = 0; i < 8; ++i) { sc[i] = expf(sc[i] - mx); sum += sc[i]; }
  red[t] = sum; __syncthreads();
  for (int o = 128; o > 0; o >>= 1) {
    if (t < o) red[t] += red[t + o];
    __syncthreads();
  }
  float inv = 1.f / red[0];
#pragma unroll
  for (int i = 0; i < 8; ++i) {
    int s_ = t + i * 256;
    size_t r = (size_t)s_ * BAT + b_;
    float w = sc[i] * inv;
    scores[r] = w;
    out_attn[r] = w;
    out_attn[MROWS + r] = w;
  }
}

// ---------------- Kernel F: context partials over s-chunks (fp32 value) ----------------
__global__ void k_ctx(const float* __restrict__ value,   // [MROWS][1024] fp32
                      const float* __restrict__ scores,  // [MROWS]
                      float* __restrict__ pctx)          // [16][BAT][1024]
{
  int b_ = blockIdx.x;   // 0..31
  int sch = blockIdx.y;  // 0..7
  int t = threadIdx.x;
  int d8 = t & 127;
  int sr = t >> 7;
  float acc[8];
#pragma unroll
  for (int j = 0; j < 8; ++j) acc[j] = 0.f;
  int s0 = sch * 256;
  for (int i = 0; i < 128; ++i) {
    int s_ = s0 + i * 2 + sr;
    size_t r = (size_t)s_ * BAT + b_;
    float w = scores[r];
    const float4* p = reinterpret_cast<const float4*>(value + r * 1024 + d8 * 8);
    float4 a = p[0], b = p[1];
    acc[0] += w * a.x; acc[1] += w * a.y; acc[2] += w * a.z; acc[3] += w * a.w;
    acc[4] += w * b.x; acc[5] += w * b.y; acc[6] += w * b.z; acc[7] += w * b.w;
  }
  float* dst = pctx + ((size_t)(sch * 2 + sr) * BAT + b_) * 1024 + d8 * 8;
#pragma unroll
  for (int j = 0; j < 8; ++j) dst[j] = acc[j];
}

// ---------------- Kernel G: final context reduce ----------------
__global__ void k_ctx_reduce(const float* __restrict__ pctx, float* __restrict__ out) {
  int i = blockIdx.x * 256 + threadIdx.x;  // 0..32767
  float s = 0.f;
#pragma unroll
  for (int c = 0; c < 16; ++c) s += pctx[(size_t)c * 32768 + i];
  out[i] = s;
}

extern "C" void kernel_launch(void* const* d_in, const int* in_sizes, int n_in,
                              void* d_out, int out_size, void* d_ws, size_t ws_size,
                              hipStream_t stream) {
  const float* query = (const float*)d_in[0];
  const float* value = (const float*)d_in[1];
  const float* Wq    = (const float*)d_in[2];
  const float* Wv    = (const float*)d_in[3];
  const float* v     = (const float*)d_in[4];
  const float* bias  = (const float*)d_in[5];
  const float* g     = (const float*)d_in[6];
  const unsigned char* mask = (const unsigned char*)d_in[7];
  float* out = (float*)d_out;

  char* ws = (char*)d_ws;
  unsigned short* Wvb = (unsigned short*)ws;                        // 2 MB
  float* pqb    = (float*)(ws + 2097152);                           // 128 KB
  float* nv     = pqb + 32 * 1024;                                  // 4 KB
  float* part   = nv + 1024;                                        // 4*65536*4 = 1 MB
  float* scores = part + 4 * MROWS;                                 // 256 KB
  float* pctx   = scores + MROWS;                                   // 2 MB

  k_nv<<<1, 256, 0, stream>>>(v, g, nv);
  k_pqb<<<1024, 256, 0, stream>>>(query, Wq, bias, pqb);
  k_cvt<<<512, 256, 0, stream>>>(Wv, Wvb, (long long)(1024LL * 1024 / 8));
  k_gemm<<<1024, 512, 0, stream>>>(value, Wvb, pqb, nv, part);
  k_softmax<<<32, 256, 0, stream>>>(part, mask, scores, out + 32768);
  dim3 gf(32, 8);
  k_ctx<<<gf, 256, 0, stream>>>(value, scores, pctx);
  k_ctx_reduce<<<128, 256, 0, stream>>>(pctx, out);
}